// Round 1
// baseline (243.841 us; speedup 1.0000x reference)
//
#include <hip/hip_runtime.h>

#define TPB 256

__global__ __launch_bounds__(TPB) void conv_policy_kernel(
    const float* __restrict__ x,
    const float* __restrict__ fow,   // (2,4)
    const float* __restrict__ fob,   // (2,)
    const float* __restrict__ few,   // (2,2)
    const float* __restrict__ feb,   // (2,)
    const float* __restrict__ w1,    // (1,2,3)
    const float* __restrict__ b1,    // (1,)
    const float* __restrict__ w2,    // (1,1,2)
    const float* __restrict__ b2,    // (1,)
    const float* __restrict__ dw1,   // (1,1,2)
    const float* __restrict__ db1,   // (1,)
    const float* __restrict__ dw2,   // (1,1,3)
    const float* __restrict__ db2,   // (1,)
    float* __restrict__ out,
    int n)
{
    __shared__ __align__(16) float lds[TPB * 18];   // 18 KB, reused for output staging
    const int tid  = threadIdx.x;
    const int base = blockIdx.x * TPB;              // first row of this block
    const bool full = (base + TPB) <= n;

    // ---- stage 256 rows (4608 floats) of x into LDS, coalesced ----
    if (full) {
        const float4* src = (const float4*)(x + (size_t)base * 18);
        float4*       dst = (float4*)lds;
        #pragma unroll
        for (int k = 0; k < 5; ++k) {
            int idx = k * TPB + tid;                // 1152 float4 total
            if (idx < (TPB * 18) / 4) dst[idx] = src[idx];
        }
    } else {
        const int total = n * 18;
        #pragma unroll
        for (int k = 0; k < 18; ++k) {
            int idx = k * TPB + tid;
            int g   = base * 18 + idx;
            if (g < total) lds[idx] = x[g];
        }
    }
    __syncthreads();

    // ---- per-thread row compute ----
    float r[18];
    #pragma unroll
    for (int i = 0; i < 18; ++i) r[i] = lds[tid * 18 + i];

    // weights: wave-uniform addresses -> scalar loads, L1/L2 resident
    const float b1v = b1[0], b2v = b2[0], db1v = db1[0], db2v = db2[0];
    const float w10 = w1[0], w11 = w1[1], w12 = w1[2], w13 = w1[3], w14 = w1[4], w15 = w1[5];
    const float w20 = w2[0], w21 = w2[1];
    const float dw10 = dw1[0], dw11 = dw1[1];
    const float dw20 = dw2[0], dw21 = dw2[1], dw22 = dw2[2];

    // fc_obs: (2,4) @ obs
    float fo0 = fmaxf(r[0]*fow[0] + r[1]*fow[1] + r[2]*fow[2] + r[3]*fow[3] + fob[0], 0.f);
    float fo1 = fmaxf(r[0]*fow[4] + r[1]*fow[5] + r[2]*fow[6] + r[3]*fow[7] + fob[1], 0.f);

    // conv1: stride 2, K=3, channels j=r[4..10], jd=r[11..17]
    float c1[3];
    #pragma unroll
    for (int p = 0; p < 3; ++p) {
        float s = r[4  + 2*p] * w10 + r[5  + 2*p] * w11 + r[6  + 2*p] * w12
                + r[11 + 2*p] * w13 + r[12 + 2*p] * w14 + r[13 + 2*p] * w15 + b1v;
        c1[p] = fmaxf(s, 0.f);
    }

    // conv2: stride 1, K=2
    float c20 = fmaxf(c1[0]*w20 + c1[1]*w21 + b2v, 0.f);
    float c21 = fmaxf(c1[1]*w20 + c1[2]*w21 + b2v, 0.f);

    // fc_emb
    float t0 = fo0 + c20, t1 = fo1 + c21;
    float e0 = fmaxf(t0*few[0] + t1*few[1] + feb[0], 0.f);
    float e1 = fmaxf(t0*few[2] + t1*few[3] + feb[1], 0.f);

    // deconv1: stride 1, K=2 (adjoint) -> 3 elems
    float d0 = fmaxf(e0*dw10 + db1v, 0.f);
    float d1 = fmaxf(e0*dw11 + e1*dw10 + db1v, 0.f);
    float d2 = fmaxf(e1*dw11 + db1v, 0.f);

    // deconv2: stride 2, K=3 (adjoint) -> 7 elems, no relu
    float o[7];
    o[0] = d0*dw20 + db2v;
    o[1] = d0*dw21 + db2v;
    o[2] = d0*dw22 + d1*dw20 + db2v;
    o[3] = d1*dw21 + db2v;
    o[4] = d1*dw22 + d2*dw20 + db2v;
    o[5] = d2*dw21 + db2v;
    o[6] = d2*dw22 + db2v;

    // ---- stage outputs in LDS, then coalesced store ----
    __syncthreads();   // everyone done reading lds before we overwrite it
    #pragma unroll
    for (int q = 0; q < 7; ++q) lds[tid * 7 + q] = o[q];
    __syncthreads();

    if (full) {
        float4*       dst = (float4*)(out + (size_t)base * 7);
        const float4* src = (const float4*)lds;
        #pragma unroll
        for (int k = 0; k < 2; ++k) {
            int idx = k * TPB + tid;                // 448 float4 total
            if (idx < (TPB * 7) / 4) dst[idx] = src[idx];
        }
    } else {
        const int total = n * 7;
        #pragma unroll
        for (int k = 0; k < 7; ++k) {
            int idx = k * TPB + tid;
            int g   = base * 7 + idx;
            if (g < total) out[g] = lds[idx];
        }
    }
}

extern "C" void kernel_launch(void* const* d_in, const int* in_sizes, int n_in,
                              void* d_out, int out_size, void* d_ws, size_t ws_size,
                              hipStream_t stream) {
    const float* x   = (const float*)d_in[0];
    const float* fow = (const float*)d_in[1];
    const float* fob = (const float*)d_in[2];
    const float* few = (const float*)d_in[3];
    const float* feb = (const float*)d_in[4];
    const float* w1  = (const float*)d_in[5];
    const float* b1  = (const float*)d_in[6];
    const float* w2  = (const float*)d_in[7];
    const float* b2  = (const float*)d_in[8];
    const float* dw1 = (const float*)d_in[9];
    const float* db1 = (const float*)d_in[10];
    const float* dw2 = (const float*)d_in[11];
    const float* db2 = (const float*)d_in[12];
    float* out = (float*)d_out;

    const int n    = in_sizes[0] / 18;
    const int grid = (n + TPB - 1) / TPB;
    conv_policy_kernel<<<grid, TPB, 0, stream>>>(
        x, fow, fob, few, feb, w1, b1, w2, b2, dw1, db1, dw2, db2, out, n);
}

// Round 3
// 242.331 us; speedup vs baseline: 1.0062x; 1.0062x over previous
//
#include <hip/hip_runtime.h>

#define TPB 256

typedef float v4f __attribute__((ext_vector_type(4)));   // clang vector: valid for nontemporal builtins

__global__ __launch_bounds__(TPB) void conv_policy_kernel(
    const float* __restrict__ x,
    const float* __restrict__ fow,   // (2,4)
    const float* __restrict__ fob,   // (2,)
    const float* __restrict__ few,   // (2,2)
    const float* __restrict__ feb,   // (2,)
    const float* __restrict__ w1,    // (1,2,3)
    const float* __restrict__ b1,    // (1,)
    const float* __restrict__ w2,    // (1,1,2)
    const float* __restrict__ b2,    // (1,)
    const float* __restrict__ dw1,   // (1,1,2)
    const float* __restrict__ db1,   // (1,)
    const float* __restrict__ dw2,   // (1,1,3)
    const float* __restrict__ db2,   // (1,)
    float* __restrict__ out,
    int n)
{
    __shared__ __align__(16) float lds[TPB * 18];   // 18 KB, reused for output staging
    const int tid  = threadIdx.x;
    const int base = blockIdx.x * TPB;
    const bool full = (base + TPB) <= n;

    // ---- hoist all weight loads: scalar/uniform, overlap with staging DMA ----
    const float fow0=fow[0],fow1=fow[1],fow2=fow[2],fow3=fow[3];
    const float fow4=fow[4],fow5=fow[5],fow6=fow[6],fow7=fow[7];
    const float fob0=fob[0],fob1=fob[1];
    const float few0=few[0],few1=few[1],few2=few[2],few3=few[3];
    const float feb0=feb[0],feb1=feb[1];
    const float w10=w1[0],w11=w1[1],w12=w1[2],w13=w1[3],w14=w1[4],w15=w1[5];
    const float b1v=b1[0], b2v=b2[0], db1v=db1[0], db2v=db2[0];
    const float w20=w2[0],w21=w2[1];
    const float dw10=dw1[0],dw11=dw1[1];
    const float dw20=dw2[0],dw21=dw2[1],dw22=dw2[2];

    // ---- stage 256 rows (4608 floats = 1152 float4) into LDS ----
    if (full) {
        // async global->LDS DMA, 16 B/lane; LDS dest = wave-uniform base + lane*16
        const float4* src = (const float4*)(x + (size_t)base * 18);
        const int wave = tid >> 6;
        #pragma unroll
        for (int k = 0; k < 4; ++k) {
            int idx = k * TPB + tid;                       // 1024 float4
            __builtin_amdgcn_global_load_lds(
                (const __attribute__((address_space(1))) void*)(src + idx),
                (__attribute__((address_space(3))) void*)(lds + (size_t)(k * TPB + wave * 64) * 4),
                16, 0, 0);
        }
        if (tid < 128) {                                   // remaining 128 float4 (waves 0,1)
            int idx = 4 * TPB + tid;
            __builtin_amdgcn_global_load_lds(
                (const __attribute__((address_space(1))) void*)(src + idx),
                (__attribute__((address_space(3))) void*)(lds + (size_t)(4 * TPB + wave * 64) * 4),
                16, 0, 0);
        }
    } else {
        const int total = n * 18;
        for (int k = 0; k < 18; ++k) {
            int idx = k * TPB + tid;
            int g   = base * 18 + idx;
            if (g < total) lds[idx] = x[g];
        }
    }
    __syncthreads();   // drains vmcnt for the LDS-DMA before reads

    // ---- per-thread row compute; row base is 72 B -> 8B-aligned: ds_read_b64 x9 ----
    float r[18];
    {
        const float2* rowp = (const float2*)(lds + tid * 18);
        #pragma unroll
        for (int i = 0; i < 9; ++i) { float2 v = rowp[i]; r[2*i] = v.x; r[2*i+1] = v.y; }
    }

    // fc_obs: (2,4) @ obs
    float fo0 = fmaxf(r[0]*fow0 + r[1]*fow1 + r[2]*fow2 + r[3]*fow3 + fob0, 0.f);
    float fo1 = fmaxf(r[0]*fow4 + r[1]*fow5 + r[2]*fow6 + r[3]*fow7 + fob1, 0.f);

    // conv1: stride 2, K=3, in-channels j=r[4..10], jd=r[11..17]
    float c1[3];
    #pragma unroll
    for (int p = 0; p < 3; ++p) {
        float s = r[4  + 2*p] * w10 + r[5  + 2*p] * w11 + r[6  + 2*p] * w12
                + r[11 + 2*p] * w13 + r[12 + 2*p] * w14 + r[13 + 2*p] * w15 + b1v;
        c1[p] = fmaxf(s, 0.f);
    }

    // conv2: stride 1, K=2
    float c20 = fmaxf(c1[0]*w20 + c1[1]*w21 + b2v, 0.f);
    float c21 = fmaxf(c1[1]*w20 + c1[2]*w21 + b2v, 0.f);

    // fc_emb
    float t0 = fo0 + c20, t1 = fo1 + c21;
    float e0 = fmaxf(t0*few0 + t1*few1 + feb0, 0.f);
    float e1 = fmaxf(t0*few2 + t1*few3 + feb1, 0.f);

    // deconv1: stride 1, K=2 (adjoint) -> 3 elems
    float d0 = fmaxf(e0*dw10 + db1v, 0.f);
    float d1 = fmaxf(e0*dw11 + e1*dw10 + db1v, 0.f);
    float d2 = fmaxf(e1*dw11 + db1v, 0.f);

    // deconv2: stride 2, K=3 (adjoint) -> 7 elems, no relu
    float o[7];
    o[0] = d0*dw20 + db2v;
    o[1] = d0*dw21 + db2v;
    o[2] = d0*dw22 + d1*dw20 + db2v;
    o[3] = d1*dw21 + db2v;
    o[4] = d1*dw22 + d2*dw20 + db2v;
    o[5] = d2*dw21 + db2v;
    o[6] = d2*dw22 + db2v;

    // ---- stage outputs in LDS, then coalesced nontemporal stores ----
    __syncthreads();   // all reads of lds done before overwrite
    #pragma unroll
    for (int q = 0; q < 7; ++q) lds[tid * 7 + q] = o[q];
    __syncthreads();

    if (full) {
        v4f*       dst  = (v4f*)(out + (size_t)base * 7);
        const v4f* srcl = (const v4f*)lds;                  // 448 v4f total
        __builtin_nontemporal_store(srcl[tid], dst + tid);
        if (tid < 192)
            __builtin_nontemporal_store(srcl[TPB + tid], dst + TPB + tid);
    } else {
        const int total = n * 7;
        for (int k = 0; k < 7; ++k) {
            int idx = k * TPB + tid;
            int g   = base * 7 + idx;
            if (g < total) out[g] = lds[idx];
        }
    }
}

extern "C" void kernel_launch(void* const* d_in, const int* in_sizes, int n_in,
                              void* d_out, int out_size, void* d_ws, size_t ws_size,
                              hipStream_t stream) {
    const float* x   = (const float*)d_in[0];
    const float* fow = (const float*)d_in[1];
    const float* fob = (const float*)d_in[2];
    const float* few = (const float*)d_in[3];
    const float* feb = (const float*)d_in[4];
    const float* w1  = (const float*)d_in[5];
    const float* b1  = (const float*)d_in[6];
    const float* w2  = (const float*)d_in[7];
    const float* b2  = (const float*)d_in[8];
    const float* dw1 = (const float*)d_in[9];
    const float* db1 = (const float*)d_in[10];
    const float* dw2 = (const float*)d_in[11];
    const float* db2 = (const float*)d_in[12];
    float* out = (float*)d_out;

    const int n    = in_sizes[0] / 18;
    const int grid = (n + TPB - 1) / TPB;
    conv_policy_kernel<<<grid, TPB, 0, stream>>>(
        x, fow, fob, few, feb, w1, b1, w2, b2, dw1, db1, dw2, db2, out, n);
}

// Round 4
// 241.640 us; speedup vs baseline: 1.0091x; 1.0029x over previous
//
#include <hip/hip_runtime.h>

#define TPB 256

typedef float v4f __attribute__((ext_vector_type(4)));

// s_waitcnt immediates (gfx9/CDNA encoding: vmcnt[3:0]+[15:14], expcnt[6:4], lgkmcnt[11:8])
#define WAITCNT_VM0   0x0F70   // vmcnt(0), lgkm/exp don't-care
#define WAITCNT_LGKM0 0xC07F   // lgkmcnt(0), vm/exp don't-care

struct Wts {
    float fow0,fow1,fow2,fow3,fow4,fow5,fow6,fow7,fob0,fob1;
    float few0,few1,few2,few3,feb0,feb1;
    float w10,w11,w12,w13,w14,w15,b1v,b2v;
    float w20,w21,dw10,dw11,db1v,db2v,dw20,dw21,dw22;
};

__device__ __forceinline__ void compute_row(const float r[18], const Wts& W, float o[7]) {
    // fc_obs
    float fo0 = fmaxf(r[0]*W.fow0 + r[1]*W.fow1 + r[2]*W.fow2 + r[3]*W.fow3 + W.fob0, 0.f);
    float fo1 = fmaxf(r[0]*W.fow4 + r[1]*W.fow5 + r[2]*W.fow6 + r[3]*W.fow7 + W.fob1, 0.f);
    // conv1: stride 2, K=3, channels j=r[4..10], jd=r[11..17]
    float c1[3];
    #pragma unroll
    for (int p = 0; p < 3; ++p) {
        float s = r[4  + 2*p]*W.w10 + r[5  + 2*p]*W.w11 + r[6  + 2*p]*W.w12
                + r[11 + 2*p]*W.w13 + r[12 + 2*p]*W.w14 + r[13 + 2*p]*W.w15 + W.b1v;
        c1[p] = fmaxf(s, 0.f);
    }
    // conv2: stride 1, K=2
    float c20 = fmaxf(c1[0]*W.w20 + c1[1]*W.w21 + W.b2v, 0.f);
    float c21 = fmaxf(c1[1]*W.w20 + c1[2]*W.w21 + W.b2v, 0.f);
    // fc_emb
    float t0 = fo0 + c20, t1 = fo1 + c21;
    float e0 = fmaxf(t0*W.few0 + t1*W.few1 + W.feb0, 0.f);
    float e1 = fmaxf(t0*W.few2 + t1*W.few3 + W.feb1, 0.f);
    // deconv1 (adjoint, K=2, s=1)
    float d0 = fmaxf(e0*W.dw10 + W.db1v, 0.f);
    float d1 = fmaxf(e0*W.dw11 + e1*W.dw10 + W.db1v, 0.f);
    float d2 = fmaxf(e1*W.dw11 + W.db1v, 0.f);
    // deconv2 (adjoint, K=3, s=2), no relu
    o[0] = d0*W.dw20 + W.db2v;
    o[1] = d0*W.dw21 + W.db2v;
    o[2] = d0*W.dw22 + d1*W.dw20 + W.db2v;
    o[3] = d1*W.dw21 + W.db2v;
    o[4] = d1*W.dw22 + d2*W.dw20 + W.db2v;
    o[5] = d2*W.dw21 + W.db2v;
    o[6] = d2*W.dw22 + W.db2v;
}

__global__ __launch_bounds__(TPB) void conv_policy_kernel(
    const float* __restrict__ x,
    const float* __restrict__ fow, const float* __restrict__ fob,
    const float* __restrict__ few, const float* __restrict__ feb,
    const float* __restrict__ w1,  const float* __restrict__ b1,
    const float* __restrict__ w2,  const float* __restrict__ b2,
    const float* __restrict__ dw1, const float* __restrict__ db1,
    const float* __restrict__ dw2, const float* __restrict__ db2,
    float* __restrict__ out, int n)
{
    // 4 waves x 64 rows x 18 floats; each wave owns a 4608 B slice.  No __syncthreads anywhere.
    __shared__ __align__(16) float lds[TPB * 18];
    const int tid     = threadIdx.x;
    const int lane    = tid & 63;
    const int wave    = tid >> 6;
    const int base    = blockIdx.x * TPB;
    const int rowbase = base + wave * 64;          // this wave's first row

    if (rowbase >= n) return;                      // empty tail wave: nothing to do

    const bool wfull = (rowbase + 64) <= n;

    float* ldsw = lds + wave * 1152;               // wave's private 1152-float slice

    if (wfull) {
        // ---- per-wave async DMA: 288 float4 (4 full insts + half inst) ----
        const float4* src4 = (const float4*)(x + (size_t)rowbase * 18);
        #pragma unroll
        for (int k = 0; k < 4; ++k) {
            __builtin_amdgcn_global_load_lds(
                (const __attribute__((address_space(1))) void*)(src4 + k * 64 + lane),
                (__attribute__((address_space(3))) void*)(ldsw + k * 256),
                16, 0, 0);
        }
        if (lane < 32) {
            __builtin_amdgcn_global_load_lds(
                (const __attribute__((address_space(1))) void*)(src4 + 256 + lane),
                (__attribute__((address_space(3))) void*)(ldsw + 1024),
                16, 0, 0);
        }
    }

    // ---- weights: wave-uniform scalar loads, overlap with in-flight DMA ----
    Wts W;
    W.fow0=fow[0];W.fow1=fow[1];W.fow2=fow[2];W.fow3=fow[3];
    W.fow4=fow[4];W.fow5=fow[5];W.fow6=fow[6];W.fow7=fow[7];
    W.fob0=fob[0];W.fob1=fob[1];
    W.few0=few[0];W.few1=few[1];W.few2=few[2];W.few3=few[3];
    W.feb0=feb[0];W.feb1=feb[1];
    W.w10=w1[0];W.w11=w1[1];W.w12=w1[2];W.w13=w1[3];W.w14=w1[4];W.w15=w1[5];
    W.b1v=b1[0];W.b2v=b2[0];
    W.w20=w2[0];W.w21=w2[1];
    W.dw10=dw1[0];W.dw11=dw1[1];W.db1v=db1[0];W.db2v=db2[0];
    W.dw20=dw2[0];W.dw21=dw2[1];W.dw22=dw2[2];

    if (wfull) {
        // wave-level drain of the LDS-DMA (no block barrier needed: slice is wave-private)
        __builtin_amdgcn_s_waitcnt(WAITCNT_VM0);
        __builtin_amdgcn_wave_barrier();

        // ---- row read: 9x ds_read_b64 (72 B row base, 8B-aligned) ----
        float r[18];
        const float2* rowp = (const float2*)(ldsw + lane * 18);
        #pragma unroll
        for (int i = 0; i < 9; ++i) { float2 v = rowp[i]; r[2*i] = v.x; r[2*i+1] = v.y; }

        float o[7];
        compute_row(r, W, o);

        // ---- in-place per-wave output transpose (448 floats < 1152 slice) ----
        __builtin_amdgcn_s_waitcnt(WAITCNT_LGKM0);   // all row reads landed in regs
        __builtin_amdgcn_wave_barrier();
        #pragma unroll
        for (int q = 0; q < 7; ++q) ldsw[lane * 7 + q] = o[q];
        __builtin_amdgcn_s_waitcnt(WAITCNT_LGKM0);   // writes visible to own wave's reads
        __builtin_amdgcn_wave_barrier();

        // ---- coalesced NT stores: 112 v4f per wave ----
        v4f*       dst  = (v4f*)(out + (size_t)rowbase * 7);   // 1792 B/wave, 16B-aligned
        const v4f* vsrc = (const v4f*)ldsw;
        __builtin_nontemporal_store(vsrc[lane], dst + lane);
        if (lane < 48)
            __builtin_nontemporal_store(vsrc[64 + lane], dst + 64 + lane);
    } else {
        // partial wave (n % 64 != 0 only): scalar fallback, no LDS
        int row = rowbase + lane;
        if (row < n) {
            float r[18];
            #pragma unroll
            for (int i = 0; i < 18; ++i) r[i] = x[(size_t)row * 18 + i];
            float o[7];
            compute_row(r, W, o);
            #pragma unroll
            for (int q = 0; q < 7; ++q) out[(size_t)row * 7 + q] = o[q];
        }
    }
}

extern "C" void kernel_launch(void* const* d_in, const int* in_sizes, int n_in,
                              void* d_out, int out_size, void* d_ws, size_t ws_size,
                              hipStream_t stream) {
    const float* x   = (const float*)d_in[0];
    const float* fow = (const float*)d_in[1];
    const float* fob = (const float*)d_in[2];
    const float* few = (const float*)d_in[3];
    const float* feb = (const float*)d_in[4];
    const float* w1  = (const float*)d_in[5];
    const float* b1  = (const float*)d_in[6];
    const float* w2  = (const float*)d_in[7];
    const float* b2  = (const float*)d_in[8];
    const float* dw1 = (const float*)d_in[9];
    const float* db1 = (const float*)d_in[10];
    const float* dw2 = (const float*)d_in[11];
    const float* db2 = (const float*)d_in[12];
    float* out = (float*)d_out;

    const int n    = in_sizes[0] / 18;
    const int grid = (n + TPB - 1) / TPB;
    conv_policy_kernel<<<grid, TPB, 0, stream>>>(
        x, fow, fob, few, feb, w1, b1, w2, b2, dw1, db1, dw2, db2, out, n);
}